// Round 3
// baseline (84.246 us; speedup 1.0000x reference)
//
#include <hip/hip_runtime.h>
#include <math.h>

#define B_ 2
#define T_ 4096
#define N_ 128
#define L_ 64
#define CT 64              // t-chunk per block
#define NC (T_/CT)         // 64 chunks per batch

constexpr float GAMMA_ = 0.75f;
constexpr float EPS_ = 1e-6f;

// ---------------------------------------------------------------------------
// Fused transform + partial matmul.
// Grid: B_ * NC * 2 halves = 256 blocks, 256 threads.
// Block (b, c, h): t-range [c*64, c*64+64), n-range [h*64, h*64+64), all 64 m.
//
// Phase 1: float4 global loads; transform preds -> pdx (p), pdy (A-Bv) in LDS
//          (odd stride 65 => (n+t)%32 banks, 2-way = free); targets staged
//          [t][m] (pad 68) so phase 2 reads them as ds_read_b128.
// Phase 2: register-tiled 4n x 4m x {tp,dd} partial matmul over the 64-t chunk.
//          m-quad thread mapping (m = 4*jm+s) => float4 C stores.
// Outputs: Cp_tp/Cp_dd [b][c][n][m], sumPp/sumBp [b][n][c], sumTp [b][m][c].
// ---------------------------------------------------------------------------
__global__ void __launch_bounds__(256)
k_fused(const float* __restrict__ preds, const float* __restrict__ targets,
        float* __restrict__ Cp_tp, float* __restrict__ Cp_dd,
        float* __restrict__ sumPp, float* __restrict__ sumBp,
        float* __restrict__ sumTp) {
    int bid = blockIdx.x;
    int b = bid >> 7;              // 128 blocks per batch
    int c = (bid >> 1) & (NC - 1);
    int h = bid & 1;
    int tid = threadIdx.x;

    __shared__ float pdx[64][CT + 1];   // p,     [local n][t]  16.6 KB
    __shared__ float pdy[64][CT + 1];   // A-Bv,  [local n][t]  16.6 KB
    __shared__ float gs[CT][68];        // tgt,   [t][m] pad68  17.4 KB
    __shared__ float redA[16][65];
    __shared__ float redB[16][65];
    __shared__ float redT[16][65];

    int q4 = tid & 15;             // quad index along fast dim (n or m)
    int tq = tid >> 4;             // 0..15 base t

    // ---- phase 1a: preds chunk (64 t x 64 n), float4 loads ----
    const float* pb = preds + ((size_t)b * T_ + (size_t)c * CT) * N_ + h * 64;
    float sA[4] = {0.f, 0.f, 0.f, 0.f};
    float sB[4] = {0.f, 0.f, 0.f, 0.f};
#pragma unroll
    for (int i = 0; i < 4; ++i) {
        int t = tq + 16 * i;
        float4 x4 = *(const float4*)&pb[(size_t)t * N_ + 4 * q4];
        float xs[4] = {x4.x, x4.y, x4.z, x4.w};
#pragma unroll
        for (int j = 0; j < 4; ++j) {
            float x = xs[j];
            float e = expf(-x);
            float p = 1.f / (1.f + e);
            float spn = log1pf(e);         // softplus(-x)
            float spp = x + spn;           // softplus(x)
            float A  = sqrtf(sqrtf(1.f - p + EPS_)) * spn;   // ^0.25
            float Bv = sqrtf(sqrtf(p + EPS_)) * spp;
            pdx[4 * q4 + j][t] = p;
            pdy[4 * q4 + j][t] = A - Bv;
            sA[j] += p;
            sB[j] += Bv;
        }
    }
#pragma unroll
    for (int j = 0; j < 4; ++j) {
        redA[tq][4 * q4 + j] = sA[j];
        redB[tq][4 * q4 + j] = sB[j];
    }

    // ---- phase 1b: targets chunk (64 t x 64 m), float4 loads, [t][m] LDS ----
    const float* tb = targets + ((size_t)b * T_ + (size_t)c * CT) * L_;
    float sT[4] = {0.f, 0.f, 0.f, 0.f};
#pragma unroll
    for (int i = 0; i < 4; ++i) {
        int t = tq + 16 * i;
        float4 g4 = *(const float4*)&tb[(size_t)t * L_ + 4 * q4];
        *(float4*)&gs[t][4 * q4] = g4;
        sT[0] += g4.x; sT[1] += g4.y; sT[2] += g4.z; sT[3] += g4.w;
    }
#pragma unroll
    for (int j = 0; j < 4; ++j) redT[tq][4 * q4 + j] = sT[j];
    __syncthreads();

    // ---- per-chunk sum outputs ----
    if (tid < 64) {
        float s1 = 0.f, s2 = 0.f;
#pragma unroll
        for (int k = 0; k < 16; ++k) { s1 += redA[k][tid]; s2 += redB[k][tid]; }
        size_t o = ((size_t)b * N_ + h * 64 + tid) * NC + c;
        sumPp[o] = s1;
        sumBp[o] = s2;
    } else if (h == 0 && tid < 128) {
        int mm = tid - 64;
        float s = 0.f;
#pragma unroll
        for (int k = 0; k < 16; ++k) s += redT[k][mm];
        sumTp[((size_t)b * L_ + mm) * NC + c] = s;
    }

    // ---- phase 2: register-tiled partial matmul ----
    int in = tid >> 4;             // n-tile 0..15 (4 n each)
    int jm = tid & 15;             // m-quad: m = 4*jm + s
    float atp[4][4] = {{0.f}};
    float add_[4][4] = {{0.f}};
#pragma unroll 2
    for (int t = 0; t < CT; ++t) {
        float4 gv = *(float4*)&gs[t][4 * jm];
        float gvs[4] = {gv.x, gv.y, gv.z, gv.w};
        float px[4], py[4];
#pragma unroll
        for (int r = 0; r < 4; ++r) {
            px[r] = pdx[in * 4 + r][t];
            py[r] = pdy[in * 4 + r][t];
        }
#pragma unroll
        for (int r = 0; r < 4; ++r)
#pragma unroll
            for (int s = 0; s < 4; ++s) {
                atp[r][s]  = fmaf(px[r], gvs[s], atp[r][s]);
                add_[r][s] = fmaf(py[r], gvs[s], add_[r][s]);
            }
    }

#pragma unroll
    for (int r = 0; r < 4; ++r) {
        int n = h * 64 + in * 4 + r;
        size_t base = (((size_t)(b * NC + c)) * N_ + n) * L_ + 4 * jm;
        *(float4*)&Cp_tp[base] = make_float4(atp[r][0], atp[r][1], atp[r][2], atp[r][3]);
        *(float4*)&Cp_dd[base] = make_float4(add_[r][0], add_[r][1], add_[r][2], add_[r][3]);
    }
}

// ---------------------------------------------------------------------------
// Reduce partials over 64 chunks + finalize.
// Grid: B_*N_ = 256 blocks, 256 threads (q = tid>>6 splits chunk range).
// ---------------------------------------------------------------------------
__global__ void __launch_bounds__(256)
k_final(const float* __restrict__ preds_class, const float* __restrict__ weight,
        const float* __restrict__ alpha, const float* __restrict__ beta,
        const float* __restrict__ Cp_tp, const float* __restrict__ Cp_dd,
        const float* __restrict__ sumPp, const float* __restrict__ sumBp,
        const float* __restrict__ sumTp, float* __restrict__ out) {
    int bid = blockIdx.x;
    int b = bid >> 7;
    int n = bid & 127;
    int tid = threadIdx.x;
    int q = tid >> 6;              // 0..3, chunk-range split
    int m = tid & 63;

    __shared__ float rtp[4][64];
    __shared__ float rdd[4][64];
    __shared__ float rst[4][64];
    __shared__ float ssp, ssb;

    // tp/dd partials: chunks q*16..q*16+15; 64 consecutive floats per chunk
    float tp = 0.f, dd = 0.f;
#pragma unroll
    for (int k = 0; k < 16; ++k) {
        size_t o = (((size_t)(b * NC + q * 16 + k)) * N_ + n) * L_ + m;
        tp += Cp_tp[o];
        dd += Cp_dd[o];
    }
    rtp[q][m] = tp;
    rdd[q][m] = dd;

    // sumT partial: contiguous per thread
    const float* stp_ = sumTp + ((size_t)b * L_ + m) * NC + q * 16;
    float st = 0.f;
#pragma unroll
    for (int k = 0; k < 16; ++k) st += stp_[k];
    rst[q][m] = st;

    // sumP / sumB: one full wave each, shfl reduce over 64 lanes
    if (tid < 64) {
        float v = sumPp[((size_t)b * N_ + n) * NC + tid];
        for (int o = 32; o > 0; o >>= 1) v += __shfl_xor(v, o);
        if (tid == 0) ssp = v;
    } else if (tid < 128) {
        int l = tid - 64;
        float v = sumBp[((size_t)b * N_ + n) * NC + l];
        for (int o = 32; o > 0; o >>= 1) v += __shfl_xor(v, o);
        if (l == 0) ssb = v;
    }
    __syncthreads();

    if (q == 0) {
        float tpt = rtp[0][m] + rtp[1][m] + rtp[2][m] + rtp[3][m];
        float ddt = rdd[0][m] + rdd[1][m] + rdd[2][m] + rdd[3][m];
        float stt = rst[0][m] + rst[1][m] + rst[2][m] + rst[3][m];
        float sp = ssp, sb = ssb;

        float wv = weight[m];
        float ws = wv;
        for (int o = 32; o > 0; o >>= 1) ws += __shfl_xor(ws, o);

        float a  = alpha[m];
        float bb = beta[m];

        float cost_dia = (wv / ws) * (sb + ddt) * (1.0f / (float)T_);

        float fpv = sp - tpt;
        float fnv = stt - tpt;
        float tv = (tpt + EPS_) / (tpt + a * fpv + bb * fnv + EPS_);
        float cost_dice = powf(1.f - tv + EPS_, GAMMA_);

        float cls = preds_class[b * N_ + n];
        float sig = 1.f / (1.f + expf(-cls));

        out[((size_t)b * N_ + n) * L_ + m] = 5.f * cost_dia + 5.f * cost_dice - 2.f * sig;
    }
}

extern "C" void kernel_launch(void* const* d_in, const int* in_sizes, int n_in,
                              void* d_out, int out_size, void* d_ws, size_t ws_size,
                              hipStream_t stream) {
    const float* preds_mask  = (const float*)d_in[0];   // (B,T,N)
    const float* preds_class = (const float*)d_in[1];   // (B,N,1)
    const float* targets     = (const float*)d_in[2];   // (B,T,L)
    const float* weight      = (const float*)d_in[3];   // (N,)
    const float* alpha       = (const float*)d_in[4];   // (N,)
    const float* beta        = (const float*)d_in[5];   // (N,)
    float* out = (float*)d_out;

    // workspace layout (all fp32): ~8.55 MB total
    float* Cp_tp = (float*)d_ws;                          // B*NC*N*L = 1 Mi
    float* Cp_dd = Cp_tp + (size_t)B_ * N_ * NC * L_;
    float* sumPp = Cp_dd + (size_t)B_ * N_ * NC * L_;     // B*N*NC
    float* sumBp = sumPp + (size_t)B_ * N_ * NC;
    float* sumTp = sumBp + (size_t)B_ * N_ * NC;          // B*L*NC

    k_fused<<<B_ * NC * 2, 256, 0, stream>>>(preds_mask, targets,
                                             Cp_tp, Cp_dd, sumPp, sumBp, sumTp);
    k_final<<<B_ * N_, 256, 0, stream>>>(preds_class, weight, alpha, beta,
                                         Cp_tp, Cp_dd, sumPp, sumBp, sumTp, out);
}